// Round 1
// baseline (411.639 us; speedup 1.0000x reference)
//
#include <hip/hip_runtime.h>
#include <math.h>

#define K 32
#define F 128
#define H 256
#define TAB 4096
#define QB 8
#define BMAX 16

__device__ __forceinline__ float ssp(float x) {
    // jax.nn.softplus(x) - log(2)
    return fmaxf(x, 0.0f) + log1pf(expf(-fabsf(x))) - 0.69314718055994531f;
}

// ---------------- segment boundaries of sorted batch_ctx ----------------
__global__ void seg_kernel(const int* __restrict__ bc, int Nc, int* __restrict__ ctx_start) {
    int b = threadIdx.x;
    if (b > BMAX) return;
    int lo = 0, hi = Nc;
    while (lo < hi) {
        int mid = (lo + hi) >> 1;
        if (bc[mid] < b) lo = mid + 1; else hi = mid;
    }
    ctx_start[b] = lo;
}

// ---------------- ctx_feat = node_attr_ctx @ lin1_w  [Nc,H]x[H,F] ----------------
__global__ __launch_bounds__(128) void feat_kernel(const float* __restrict__ attr,
                                                   const float* __restrict__ lin1_w,
                                                   float* __restrict__ ctx_feat, int Nc) {
    const int R = 8;
    __shared__ float sa[R][H];
    int r0 = blockIdx.x * R;
    int tid = threadIdx.x;
    for (int i = tid; i < R * H; i += 128) {
        int r = i >> 8, h = i & (H - 1);
        int row = r0 + r;
        sa[r][h] = (row < Nc) ? attr[(size_t)row * H + h] : 0.0f;
    }
    __syncthreads();
    float acc[R];
#pragma unroll
    for (int r = 0; r < R; ++r) acc[r] = 0.0f;
    for (int h = 0; h < H; ++h) {
        float w = lin1_w[h * F + tid];
#pragma unroll
        for (int r = 0; r < R; ++r) acc[r] += sa[r][h] * w;
    }
#pragma unroll
    for (int r = 0; r < R; ++r) {
        int row = r0 + r;
        if (row < Nc) ctx_feat[(size_t)row * F + tid] = acc[r];
    }
}

// ---------------- W(dist) table: ssp(gs@nn1+b1)@nn2+b2 over dist grid ----------------
__global__ __launch_bounds__(128) void wtab_kernel(const float* __restrict__ nn1_w,
                                                   const float* __restrict__ nn1_b,
                                                   const float* __restrict__ nn2_w,
                                                   const float* __restrict__ nn2_b,
                                                   float* __restrict__ wtab) {
    int t = blockIdx.x;           // 0..TAB inclusive
    int f = threadIdx.x;          // 0..127
    float dist = (float)t * (10.0f / (float)TAB);
    __shared__ float gs[F];
    __shared__ float t1[F];
    const float delta = 10.0f / 127.0f;
    const float coeff = -0.5f / (delta * delta);
    float off = (float)f * delta;
    float d = dist - off;
    gs[f] = expf(coeff * d * d);
    __syncthreads();
    float acc = nn1_b[f];
    for (int j = 0; j < F; ++j) acc += gs[j] * nn1_w[j * F + f];
    t1[f] = ssp(acc);
    __syncthreads();
    float acc2 = nn2_b[f];
    for (int j = 0; j < F; ++j) acc2 += t1[j] * nn2_w[j * F + f];
    wtab[(size_t)t * F + f] = acc2;
}

// ---------------- batch-aware kNN: wave per query, top-32 across lanes 0..31 ----------------
__global__ __launch_bounds__(256) void knn_kernel(const float* __restrict__ posq,
                                                  const float* __restrict__ posc,
                                                  const int* __restrict__ bq,
                                                  const int* __restrict__ ctx_start,
                                                  int* __restrict__ nbr, int Nq) {
    int wave = threadIdx.x >> 6;
    int lane = threadIdx.x & 63;
    int q = blockIdx.x * 4 + wave;
    if (q >= Nq) return;

    float qx = posq[q * 3 + 0];
    float qy = posq[q * 3 + 1];
    float qz = posq[q * 3 + 2];
    int b = bq[q];
    int c0 = ctx_start[b];
    int c1 = ctx_start[b + 1];

    const float INF = __builtin_inff();
    float bestd = INF;       // valid in lanes 0..31
    int besti = c0;
    float thr = INF;         // current max of the 32 kept entries
    int count = 0;

    for (int base = c0; base < c1; base += 64) {
        int c = base + lane;
        float d2 = INF;
        if (c < c1) {
            float dx = qx - posc[c * 3 + 0];
            float dy = qy - posc[c * 3 + 1];
            float dz = qz - posc[c * 3 + 2];
            d2 = dx * dx + dy * dy + dz * dz;
        }
        unsigned long long mask = __ballot(d2 < thr);
        while (mask) {
            int src = __ffsll(mask) - 1;
            mask &= mask - 1;
            float dc = __shfl(d2, src);
            int ic = base + src;   // uniform
            if (count < 32) {
                if (lane == count) { bestd = dc; besti = ic; }
                count++;
                if (count == 32) {
                    float v = (lane < 32) ? bestd : -1.0f;
#pragma unroll
                    for (int o = 1; o < 64; o <<= 1) v = fmaxf(v, __shfl_xor(v, o));
                    thr = v;
                }
            } else if (dc < thr) {
                // argmax over lanes 0..31
                float v = (lane < 32) ? bestd : -1.0f;
                int vl = lane;
#pragma unroll
                for (int o = 1; o < 64; o <<= 1) {
                    float ov = __shfl_xor(v, o);
                    int ol = __shfl_xor(vl, o);
                    if (ov > v || (ov == v && ol < vl)) { v = ov; vl = ol; }
                }
                if (lane == vl) { bestd = dc; besti = ic; }
                float v2 = (lane < 32) ? bestd : -1.0f;
#pragma unroll
                for (int o = 1; o < 64; o <<= 1) v2 = fmaxf(v2, __shfl_xor(v2, o));
                thr = v2;
            }
        }
    }
    if (lane < 32) nbr[(size_t)q * K + lane] = besti;
}

// ---------------- per-query edge aggregation: acc_f = sum_k C_k * W_k[f] * a_k[f] ----------------
__global__ __launch_bounds__(128) void agg_kernel(const float* __restrict__ posq,
                                                  const float* __restrict__ posc,
                                                  const int* __restrict__ nbr,
                                                  const float* __restrict__ ctx_feat,
                                                  const float* __restrict__ wtab,
                                                  float* __restrict__ yacc,
                                                  float* __restrict__ ysc, int Nq) {
    int q = blockIdx.x;
    int f = threadIdx.x;
    __shared__ int sj[K];
    __shared__ int si0[K];
    __shared__ float sC[K];
    __shared__ float sfr[K];

    if (f < K) {
        int j = nbr[(size_t)q * K + f];
        sj[f] = j;
        float dx = posq[q * 3 + 0] - posc[j * 3 + 0];
        float dy = posq[q * 3 + 1] - posc[j * 3 + 1];
        float dz = posq[q * 3 + 2] - posc[j * 3 + 2];
        float dist = sqrtf(dx * dx + dy * dy + dz * dz);
        float C = 0.0f, fr = 0.0f;
        int i0 = 0;
        if (dist <= 10.0f) {
            C = 0.5f * (cosf(dist * 0.31415926535897931f) + 1.0f);
            float u = dist * ((float)TAB / 10.0f);
            i0 = (int)u;
            if (i0 > TAB - 1) i0 = TAB - 1;
            fr = u - (float)i0;
        }
        sC[f] = C; si0[f] = i0; sfr[f] = fr;
    }
    __syncthreads();

    float acc = 0.0f;
    float csum = 0.0f;
    for (int k = 0; k < K; ++k) {
        float C = sC[k];
        csum += C;
        if (C == 0.0f) continue;
        int i0 = si0[k];
        float fr = sfr[k];
        int j = sj[k];
        float w0 = wtab[(size_t)i0 * F + f];
        float w1 = wtab[(size_t)(i0 + 1) * F + f];
        float W = w0 + fr * (w1 - w0);
        float a = ctx_feat[(size_t)j * F + f];
        acc += C * (W * a);
    }
    yacc[(size_t)q * F + f] = acc;
    if (f == 0) ysc[q] = csum;
}

// ---------------- heads: y = acc@lin2 + sC*lin2_b; cls/prop MLPs ----------------
__global__ __launch_bounds__(128) void head_kernel(const float* __restrict__ yacc,
                                                   const float* __restrict__ ysc,
                                                   const float* __restrict__ lin2_w,
                                                   const float* __restrict__ lin2_b,
                                                   const float* __restrict__ cls1_w,
                                                   const float* __restrict__ cls1_b,
                                                   const float* __restrict__ cls2_w,
                                                   const float* __restrict__ cls2_b,
                                                   const float* __restrict__ prop1_w,
                                                   const float* __restrict__ prop1_b,
                                                   const float* __restrict__ prop2_w,
                                                   const float* __restrict__ prop2_b,
                                                   float* __restrict__ out_cls,
                                                   float* __restrict__ out_ind, int Nq) {
    int q0 = blockIdx.x * QB;
    int f = threadIdx.x;
    __shared__ float sa[QB][F];
    __shared__ float ssc[QB];
    __shared__ float sy[QB][F];
    __shared__ float sc1[QB][F];
    __shared__ float sp1[QB][F];

#pragma unroll
    for (int qq = 0; qq < QB; ++qq) {
        int q = q0 + qq;
        sa[qq][f] = (q < Nq) ? yacc[(size_t)q * F + f] : 0.0f;
    }
    if (f < QB) ssc[f] = (q0 + f < Nq) ? ysc[q0 + f] : 0.0f;
    __syncthreads();

    // y = acc @ lin2_w + sC * lin2_b
    float y[QB];
    float lb = lin2_b[f];
#pragma unroll
    for (int qq = 0; qq < QB; ++qq) y[qq] = ssc[qq] * lb;
    for (int j = 0; j < F; ++j) {
        float w = lin2_w[j * F + f];
#pragma unroll
        for (int qq = 0; qq < QB; ++qq) y[qq] += sa[qq][j] * w;
    }
#pragma unroll
    for (int qq = 0; qq < QB; ++qq) sy[qq][f] = y[qq];
    __syncthreads();

    // c1 = ssp(y@cls1+b), p1 = ssp(y@prop1+b)
    float c1[QB], p1[QB];
    float cb = cls1_b[f], pb = prop1_b[f];
#pragma unroll
    for (int qq = 0; qq < QB; ++qq) { c1[qq] = cb; p1[qq] = pb; }
    for (int j = 0; j < F; ++j) {
        float wc = cls1_w[j * F + f];
        float wp = prop1_w[j * F + f];
#pragma unroll
        for (int qq = 0; qq < QB; ++qq) {
            float yv = sy[qq][j];
            c1[qq] += yv * wc;
            p1[qq] += yv * wp;
        }
    }
#pragma unroll
    for (int qq = 0; qq < QB; ++qq) {
        sc1[qq][f] = ssp(c1[qq]);
        sp1[qq][f] = ssp(p1[qq]);
    }
    __syncthreads();

    // tails: 7 cls outputs + 8 ind outputs per query
    int qq = f >> 4;
    int c = f & 15;
    int q = q0 + qq;
    if (q < Nq) {
        if (c < 7) {
            float acc = cls2_b[c];
            for (int j = 0; j < F; ++j) acc += sc1[qq][j] * cls2_w[j * 7 + c];
            out_cls[(size_t)q * 7 + c] = acc;
        } else if (c < 15) {
            int cc = c - 7;
            float acc = prop2_b[cc];
            for (int j = 0; j < F; ++j) acc += sp1[qq][j] * prop2_w[j * 8 + cc];
            out_ind[(size_t)q * 8 + cc] = acc;
        }
    }
}

extern "C" void kernel_launch(void* const* d_in, const int* in_sizes, int n_in,
                              void* d_out, int out_size, void* d_ws, size_t ws_size,
                              hipStream_t stream) {
    const float* posq   = (const float*)d_in[0];
    const float* posc   = (const float*)d_in[1];
    const float* attr   = (const float*)d_in[2];
    const int*   bq     = (const int*)d_in[3];
    const int*   bc     = (const int*)d_in[4];
    const float* lin1_w = (const float*)d_in[5];
    const float* lin2_w = (const float*)d_in[6];
    const float* lin2_b = (const float*)d_in[7];
    const float* nn1_w  = (const float*)d_in[8];
    const float* nn1_b  = (const float*)d_in[9];
    const float* nn2_w  = (const float*)d_in[10];
    const float* nn2_b  = (const float*)d_in[11];
    const float* cls1_w = (const float*)d_in[12];
    const float* cls1_b = (const float*)d_in[13];
    const float* cls2_w = (const float*)d_in[14];
    const float* cls2_b = (const float*)d_in[15];
    const float* prop1_w = (const float*)d_in[16];
    const float* prop1_b = (const float*)d_in[17];
    const float* prop2_w = (const float*)d_in[18];
    const float* prop2_b = (const float*)d_in[19];

    int Nq = in_sizes[0] / 3;
    int Nc = in_sizes[1] / 3;

    char* ws = (char*)d_ws;
    size_t off = 0;
    auto alloc = [&](size_t bytes) {
        off = (off + 255) & ~(size_t)255;
        void* p = ws + off;
        off += bytes;
        return p;
    };
    int*   ctx_start = (int*)alloc((BMAX + 1) * sizeof(int));
    int*   nbr       = (int*)alloc((size_t)Nq * K * sizeof(int));
    float* ctx_feat  = (float*)alloc((size_t)Nc * F * sizeof(float));
    float* wtab      = (float*)alloc((size_t)(TAB + 1) * F * sizeof(float));
    float* yacc      = (float*)alloc((size_t)Nq * F * sizeof(float));
    float* ysc       = (float*)alloc((size_t)Nq * sizeof(float));
    (void)ws_size;

    float* out_cls = (float*)d_out;
    float* out_ind = out_cls + (size_t)Nq * 7;

    seg_kernel<<<dim3(1), dim3(32), 0, stream>>>(bc, Nc, ctx_start);
    feat_kernel<<<dim3((Nc + 7) / 8), dim3(128), 0, stream>>>(attr, lin1_w, ctx_feat, Nc);
    wtab_kernel<<<dim3(TAB + 1), dim3(128), 0, stream>>>(nn1_w, nn1_b, nn2_w, nn2_b, wtab);
    knn_kernel<<<dim3((Nq + 3) / 4), dim3(256), 0, stream>>>(posq, posc, bq, ctx_start, nbr, Nq);
    agg_kernel<<<dim3(Nq), dim3(128), 0, stream>>>(posq, posc, nbr, ctx_feat, wtab, yacc, ysc, Nq);
    head_kernel<<<dim3((Nq + QB - 1) / QB), dim3(128), 0, stream>>>(
        yacc, ysc, lin2_w, lin2_b, cls1_w, cls1_b, cls2_w, cls2_b,
        prop1_w, prop1_b, prop2_w, prop2_b, out_cls, out_ind, Nq);
}

// Round 2
// 183.225 us; speedup vs baseline: 2.2466x; 2.2466x over previous
//
#include <hip/hip_runtime.h>
#include <math.h>

#define K 32
#define F 128
#define H 256
#define TAB 4096
#define QB 8
#define BMAX 16
#define NBINS 4096
#define BCAP 1024

__device__ __forceinline__ float ssp(float x) {
    // jax.nn.softplus(x) - log(2)
    return fmaxf(x, 0.0f) + log1pf(expf(-fabsf(x))) - 0.69314718055994531f;
}

// ---------------- segment boundaries of sorted batch_ctx ----------------
__global__ void seg_kernel(const int* __restrict__ bc, int Nc, int* __restrict__ ctx_start) {
    int b = threadIdx.x;
    if (b > BMAX) return;
    int lo = 0, hi = Nc;
    while (lo < hi) {
        int mid = (lo + hi) >> 1;
        if (bc[mid] < b) lo = mid + 1; else hi = mid;
    }
    ctx_start[b] = lo;
}

// ---------------- ctx_feat = node_attr_ctx @ lin1_w  [Nc,H]x[H,F] ----------------
__global__ __launch_bounds__(128) void feat_kernel(const float* __restrict__ attr,
                                                   const float* __restrict__ lin1_w,
                                                   float* __restrict__ ctx_feat, int Nc) {
    const int R = 8;
    __shared__ float sa[R][H];
    int r0 = blockIdx.x * R;
    int tid = threadIdx.x;
    for (int i = tid; i < R * H; i += 128) {
        int r = i >> 8, h = i & (H - 1);
        int row = r0 + r;
        sa[r][h] = (row < Nc) ? attr[(size_t)row * H + h] : 0.0f;
    }
    __syncthreads();
    float acc[R];
#pragma unroll
    for (int r = 0; r < R; ++r) acc[r] = 0.0f;
    for (int h = 0; h < H; ++h) {
        float w = lin1_w[h * F + tid];
#pragma unroll
        for (int r = 0; r < R; ++r) acc[r] += sa[r][h] * w;
    }
#pragma unroll
    for (int r = 0; r < R; ++r) {
        int row = r0 + r;
        if (row < Nc) ctx_feat[(size_t)row * F + tid] = acc[r];
    }
}

// ---------------- W(dist) table: ssp(gs@nn1+b1)@nn2+b2 over dist grid ----------------
__global__ __launch_bounds__(128) void wtab_kernel(const float* __restrict__ nn1_w,
                                                   const float* __restrict__ nn1_b,
                                                   const float* __restrict__ nn2_w,
                                                   const float* __restrict__ nn2_b,
                                                   float* __restrict__ wtab) {
    int t = blockIdx.x;           // 0..TAB inclusive
    int f = threadIdx.x;          // 0..127
    float dist = (float)t * (10.0f / (float)TAB);
    __shared__ float gs[F];
    __shared__ float t1[F];
    const float delta = 10.0f / 127.0f;
    const float coeff = -0.5f / (delta * delta);
    float off = (float)f * delta;
    float d = dist - off;
    gs[f] = expf(coeff * d * d);
    __syncthreads();
    float acc = nn1_b[f];
    for (int j = 0; j < F; ++j) acc += gs[j] * nn1_w[j * F + f];
    t1[f] = ssp(acc);
    __syncthreads();
    float acc2 = nn2_b[f];
    for (int j = 0; j < F; ++j) acc2 += t1[j] * nn2_w[j * F + f];
    wtab[(size_t)t * F + f] = acc2;
}

// ---------------- batch-aware kNN: block per query, 12-bit radix select ----------------
__device__ __forceinline__ unsigned d2key(const float* __restrict__ posc, int c,
                                          float qx, float qy, float qz) {
    float dx = qx - posc[c * 3 + 0];
    float dy = qy - posc[c * 3 + 1];
    float dz = qz - posc[c * 3 + 2];
    float d2 = dx * dx + dy * dy + dz * dz;
    return __float_as_uint(d2);   // d2 >= 0: uint order == float order
}

__global__ __launch_bounds__(256) void knn_kernel(const float* __restrict__ posq,
                                                  const float* __restrict__ posc,
                                                  const int* __restrict__ bq,
                                                  const int* __restrict__ ctx_start,
                                                  int* __restrict__ nbr, int Nq) {
    __shared__ unsigned hist[NBINS];
    __shared__ unsigned partial[256];
    __shared__ unsigned bkey[BCAP];
    __shared__ int bidx[BCAP];
    __shared__ int s_T, s_below;
    __shared__ unsigned s_nbelow, s_nbound;

    int q = blockIdx.x;
    if (q >= Nq) return;
    int tid = threadIdx.x;
    int lane = tid & 63;
    int wave = tid >> 6;

    for (int i = tid; i < NBINS; i += 256) hist[i] = 0;
    if (tid == 0) { s_nbelow = 0; s_nbound = 0; s_T = NBINS - 1; s_below = 0; }

    float qx = posq[q * 3 + 0];
    float qy = posq[q * 3 + 1];
    float qz = posq[q * 3 + 2];
    int b = bq[q];
    int c0 = ctx_start[b];
    int c1 = ctx_start[b + 1];
    __syncthreads();

    // Pass A: histogram of top-12-bit key
    for (int c = c0 + tid; c < c1; c += 256) {
        unsigned key = d2key(posc, c, qx, qy, qz);
        atomicAdd(&hist[key >> 20], 1u);
    }
    __syncthreads();

    // per-thread chunk sums (16 bins each)
    unsigned csum = 0;
    {
        int base = tid * 16;
#pragma unroll
        for (int i = 0; i < 16; ++i) csum += hist[base + i];
    }
    partial[tid] = csum;
    __syncthreads();

    // wave 0: scan 256 partials, locate cutoff bin T and count_below
    if (wave == 0) {
        unsigned p0 = partial[lane * 4 + 0];
        unsigned p1 = partial[lane * 4 + 1];
        unsigned p2 = partial[lane * 4 + 2];
        unsigned p3 = partial[lane * 4 + 3];
        unsigned ls = p0 + p1 + p2 + p3;
        unsigned inc = ls;
#pragma unroll
        for (int off = 1; off < 64; off <<= 1) {
            unsigned v = __shfl_up(inc, off);
            if (lane >= off) inc += v;
        }
        unsigned cb = inc - ls;  // exclusive prefix for this lane's 4 chunks
        unsigned ps[4] = {p0, p1, p2, p3};
#pragma unroll
        for (int i = 0; i < 4; ++i) {
            if (cb < (unsigned)K && cb + ps[i] >= (unsigned)K) {
                int t = lane * 4 + i;
                unsigned run = cb;
                for (int j = 0; j < 16; ++j) {
                    unsigned h = hist[t * 16 + j];
                    if (run + h >= (unsigned)K) { s_T = t * 16 + j; s_below = (int)run; break; }
                    run += h;
                }
            }
            cb += ps[i];
        }
    }
    __syncthreads();

    int T = s_T;
    int below = s_below;

    // Pass B: emit sure winners, collect boundary bin
    for (int c = c0 + tid; c < c1; c += 256) {
        unsigned key = d2key(posc, c, qx, qy, qz);
        unsigned bin = key >> 20;
        if ((int)bin < T) {
            unsigned p = atomicAdd(&s_nbelow, 1u);
            if (p < (unsigned)K) nbr[(size_t)q * K + p] = c;
        } else if ((int)bin == T) {
            unsigned p = atomicAdd(&s_nbound, 1u);
            if (p < (unsigned)BCAP) { bkey[p] = key; bidx[p] = c; }
        }
    }
    __syncthreads();

    // wave 0: pick m = K - below smallest from boundary list
    if (wave == 0) {
        int nb = (int)min(s_nbound, (unsigned)BCAP);
        int m = K - below;
        for (int it = 0; it < m; ++it) {
            unsigned bestk = 0xFFFFFFFFu;
            int bestp = -1;
            for (int p = lane; p < nb; p += 64) {
                unsigned kk = bkey[p];
                if (kk < bestk) { bestk = kk; bestp = p; }
            }
#pragma unroll
            for (int off = 1; off < 64; off <<= 1) {
                unsigned ok = __shfl_xor(bestk, off);
                int op = __shfl_xor(bestp, off);
                if (ok < bestk) { bestk = ok; bestp = op; }
            }
            if (lane == 0 && bestp >= 0) {
                nbr[(size_t)q * K + below + it] = bidx[bestp];
                bkey[bestp] = 0xFFFFFFFFu;
            }
            __asm__ volatile("" ::: "memory");
        }
    }
}

// ---------------- per-query edge aggregation: acc_f = sum_k C_k * W_k[f] * a_k[f] ----------------
__global__ __launch_bounds__(128) void agg_kernel(const float* __restrict__ posq,
                                                  const float* __restrict__ posc,
                                                  const int* __restrict__ nbr,
                                                  const float* __restrict__ ctx_feat,
                                                  const float* __restrict__ wtab,
                                                  float* __restrict__ yacc,
                                                  float* __restrict__ ysc, int Nq) {
    int q = blockIdx.x;
    int f = threadIdx.x;
    __shared__ int sj[K];
    __shared__ int si0[K];
    __shared__ float sC[K];
    __shared__ float sfr[K];

    if (f < K) {
        int j = nbr[(size_t)q * K + f];
        sj[f] = j;
        float dx = posq[q * 3 + 0] - posc[j * 3 + 0];
        float dy = posq[q * 3 + 1] - posc[j * 3 + 1];
        float dz = posq[q * 3 + 2] - posc[j * 3 + 2];
        float dist = sqrtf(dx * dx + dy * dy + dz * dz);
        float C = 0.0f, fr = 0.0f;
        int i0 = 0;
        if (dist <= 10.0f) {
            C = 0.5f * (cosf(dist * 0.31415926535897931f) + 1.0f);
            float u = dist * ((float)TAB / 10.0f);
            i0 = (int)u;
            if (i0 > TAB - 1) i0 = TAB - 1;
            fr = u - (float)i0;
        }
        sC[f] = C; si0[f] = i0; sfr[f] = fr;
    }
    __syncthreads();

    float acc = 0.0f;
    float csum = 0.0f;
    for (int k = 0; k < K; ++k) {
        float C = sC[k];
        csum += C;
        if (C == 0.0f) continue;
        int i0 = si0[k];
        float fr = sfr[k];
        int j = sj[k];
        float w0 = wtab[(size_t)i0 * F + f];
        float w1 = wtab[(size_t)(i0 + 1) * F + f];
        float W = w0 + fr * (w1 - w0);
        float a = ctx_feat[(size_t)j * F + f];
        acc += C * (W * a);
    }
    yacc[(size_t)q * F + f] = acc;
    if (f == 0) ysc[q] = csum;
}

// ---------------- heads: y = acc@lin2 + sC*lin2_b; cls/prop MLPs ----------------
__global__ __launch_bounds__(128) void head_kernel(const float* __restrict__ yacc,
                                                   const float* __restrict__ ysc,
                                                   const float* __restrict__ lin2_w,
                                                   const float* __restrict__ lin2_b,
                                                   const float* __restrict__ cls1_w,
                                                   const float* __restrict__ cls1_b,
                                                   const float* __restrict__ cls2_w,
                                                   const float* __restrict__ cls2_b,
                                                   const float* __restrict__ prop1_w,
                                                   const float* __restrict__ prop1_b,
                                                   const float* __restrict__ prop2_w,
                                                   const float* __restrict__ prop2_b,
                                                   float* __restrict__ out_cls,
                                                   float* __restrict__ out_ind, int Nq) {
    int q0 = blockIdx.x * QB;
    int f = threadIdx.x;
    __shared__ float sa[QB][F];
    __shared__ float ssc[QB];
    __shared__ float sy[QB][F];
    __shared__ float sc1[QB][F];
    __shared__ float sp1[QB][F];

#pragma unroll
    for (int qq = 0; qq < QB; ++qq) {
        int q = q0 + qq;
        sa[qq][f] = (q < Nq) ? yacc[(size_t)q * F + f] : 0.0f;
    }
    if (f < QB) ssc[f] = (q0 + f < Nq) ? ysc[q0 + f] : 0.0f;
    __syncthreads();

    // y = acc @ lin2_w + sC * lin2_b
    float y[QB];
    float lb = lin2_b[f];
#pragma unroll
    for (int qq = 0; qq < QB; ++qq) y[qq] = ssc[qq] * lb;
    for (int j = 0; j < F; ++j) {
        float w = lin2_w[j * F + f];
#pragma unroll
        for (int qq = 0; qq < QB; ++qq) y[qq] += sa[qq][j] * w;
    }
#pragma unroll
    for (int qq = 0; qq < QB; ++qq) sy[qq][f] = y[qq];
    __syncthreads();

    // c1 = ssp(y@cls1+b), p1 = ssp(y@prop1+b)
    float c1[QB], p1[QB];
    float cb = cls1_b[f], pb = prop1_b[f];
#pragma unroll
    for (int qq = 0; qq < QB; ++qq) { c1[qq] = cb; p1[qq] = pb; }
    for (int j = 0; j < F; ++j) {
        float wc = cls1_w[j * F + f];
        float wp = prop1_w[j * F + f];
#pragma unroll
        for (int qq = 0; qq < QB; ++qq) {
            float yv = sy[qq][j];
            c1[qq] += yv * wc;
            p1[qq] += yv * wp;
        }
    }
#pragma unroll
    for (int qq = 0; qq < QB; ++qq) {
        sc1[qq][f] = ssp(c1[qq]);
        sp1[qq][f] = ssp(p1[qq]);
    }
    __syncthreads();

    // tails: 7 cls outputs + 8 ind outputs per query
    int qq = f >> 4;
    int c = f & 15;
    int q = q0 + qq;
    if (q < Nq) {
        if (c < 7) {
            float acc = cls2_b[c];
            for (int j = 0; j < F; ++j) acc += sc1[qq][j] * cls2_w[j * 7 + c];
            out_cls[(size_t)q * 7 + c] = acc;
        } else if (c < 15) {
            int cc = c - 7;
            float acc = prop2_b[cc];
            for (int j = 0; j < F; ++j) acc += sp1[qq][j] * prop2_w[j * 8 + cc];
            out_ind[(size_t)q * 8 + cc] = acc;
        }
    }
}

extern "C" void kernel_launch(void* const* d_in, const int* in_sizes, int n_in,
                              void* d_out, int out_size, void* d_ws, size_t ws_size,
                              hipStream_t stream) {
    const float* posq   = (const float*)d_in[0];
    const float* posc   = (const float*)d_in[1];
    const float* attr   = (const float*)d_in[2];
    const int*   bq     = (const int*)d_in[3];
    const int*   bc     = (const int*)d_in[4];
    const float* lin1_w = (const float*)d_in[5];
    const float* lin2_w = (const float*)d_in[6];
    const float* lin2_b = (const float*)d_in[7];
    const float* nn1_w  = (const float*)d_in[8];
    const float* nn1_b  = (const float*)d_in[9];
    const float* nn2_w  = (const float*)d_in[10];
    const float* nn2_b  = (const float*)d_in[11];
    const float* cls1_w = (const float*)d_in[12];
    const float* cls1_b = (const float*)d_in[13];
    const float* cls2_w = (const float*)d_in[14];
    const float* cls2_b = (const float*)d_in[15];
    const float* prop1_w = (const float*)d_in[16];
    const float* prop1_b = (const float*)d_in[17];
    const float* prop2_w = (const float*)d_in[18];
    const float* prop2_b = (const float*)d_in[19];

    int Nq = in_sizes[0] / 3;
    int Nc = in_sizes[1] / 3;

    char* ws = (char*)d_ws;
    size_t off = 0;
    auto alloc = [&](size_t bytes) {
        off = (off + 255) & ~(size_t)255;
        void* p = ws + off;
        off += bytes;
        return p;
    };
    int*   ctx_start = (int*)alloc((BMAX + 1) * sizeof(int));
    int*   nbr       = (int*)alloc((size_t)Nq * K * sizeof(int));
    float* ctx_feat  = (float*)alloc((size_t)Nc * F * sizeof(float));
    float* wtab      = (float*)alloc((size_t)(TAB + 1) * F * sizeof(float));
    float* yacc      = (float*)alloc((size_t)Nq * F * sizeof(float));
    float* ysc       = (float*)alloc((size_t)Nq * sizeof(float));
    (void)ws_size;

    float* out_cls = (float*)d_out;
    float* out_ind = out_cls + (size_t)Nq * 7;

    seg_kernel<<<dim3(1), dim3(32), 0, stream>>>(bc, Nc, ctx_start);
    feat_kernel<<<dim3((Nc + 7) / 8), dim3(128), 0, stream>>>(attr, lin1_w, ctx_feat, Nc);
    wtab_kernel<<<dim3(TAB + 1), dim3(128), 0, stream>>>(nn1_w, nn1_b, nn2_w, nn2_b, wtab);
    knn_kernel<<<dim3(Nq), dim3(256), 0, stream>>>(posq, posc, bq, ctx_start, nbr, Nq);
    agg_kernel<<<dim3(Nq), dim3(128), 0, stream>>>(posq, posc, nbr, ctx_feat, wtab, yacc, ysc, Nq);
    head_kernel<<<dim3((Nq + QB - 1) / QB), dim3(128), 0, stream>>>(
        yacc, ysc, lin2_w, lin2_b, cls1_w, cls1_b, cls2_w, cls2_b,
        prop1_w, prop1_b, prop2_w, prop2_b, out_cls, out_ind, Nq);
}

// Round 3
// 167.602 us; speedup vs baseline: 2.4561x; 1.0932x over previous
//
#include <hip/hip_runtime.h>
#include <math.h>

#define K 32
#define F 128
#define H 256
#define TAB 4096
#define QB 8
#define BMAX 16
#define RCUT2 100.0f
#define KBINS 64
#define BINCAP 2560
#define BCAP 128

__device__ __forceinline__ float ssp(float x) {
    // jax.nn.softplus(x) - log(2)
    return fmaxf(x, 0.0f) + log1pf(expf(-fabsf(x))) - 0.69314718055994531f;
}

// d2 with pinned fma contraction so pass A and pass B agree bit-exactly
__device__ __forceinline__ float d2f4(float4 p, float qx, float qy, float qz) {
    float dx = qx - p.x;
    float dy = qy - p.y;
    float dz = qz - p.z;
    return fmaf(dz, dz, fmaf(dy, dy, dx * dx));
}

// ---------------- segment boundaries of sorted batch_ctx ----------------
__global__ void seg_kernel(const int* __restrict__ bc, int Nc, int* __restrict__ ctx_start) {
    int b = threadIdx.x;
    if (b > BMAX) return;
    int lo = 0, hi = Nc;
    while (lo < hi) {
        int mid = (lo + hi) >> 1;
        if (bc[mid] < b) lo = mid + 1; else hi = mid;
    }
    ctx_start[b] = lo;
}

// ---------------- pad positions to float4 for vector loads ----------------
__global__ __launch_bounds__(256) void pad_kernel(const float* __restrict__ pos,
                                                  float4* __restrict__ pos4, int N) {
    int i = blockIdx.x * 256 + threadIdx.x;
    if (i < N) {
        pos4[i] = make_float4(pos[i * 3 + 0], pos[i * 3 + 1], pos[i * 3 + 2], 0.0f);
    }
}

// ---------------- ctx_feat = node_attr_ctx @ lin1_w  [Nc,H]x[H,F] ----------------
__global__ __launch_bounds__(128) void feat_kernel(const float* __restrict__ attr,
                                                   const float* __restrict__ lin1_w,
                                                   float* __restrict__ ctx_feat, int Nc) {
    const int R = 8;
    __shared__ float sa[R][H];
    int r0 = blockIdx.x * R;
    int tid = threadIdx.x;
    for (int i = tid; i < R * H; i += 128) {
        int r = i >> 8, h = i & (H - 1);
        int row = r0 + r;
        sa[r][h] = (row < Nc) ? attr[(size_t)row * H + h] : 0.0f;
    }
    __syncthreads();
    float acc[R];
#pragma unroll
    for (int r = 0; r < R; ++r) acc[r] = 0.0f;
    for (int h = 0; h < H; ++h) {
        float w = lin1_w[h * F + tid];
#pragma unroll
        for (int r = 0; r < R; ++r) acc[r] += sa[r][h] * w;
    }
#pragma unroll
    for (int r = 0; r < R; ++r) {
        int row = r0 + r;
        if (row < Nc) ctx_feat[(size_t)row * F + tid] = acc[r];
    }
}

// ---------------- W(dist) table: ssp(gs@nn1+b1)@nn2+b2 over dist grid ----------------
__global__ __launch_bounds__(128) void wtab_kernel(const float* __restrict__ nn1_w,
                                                   const float* __restrict__ nn1_b,
                                                   const float* __restrict__ nn2_w,
                                                   const float* __restrict__ nn2_b,
                                                   float* __restrict__ wtab) {
    int t = blockIdx.x;           // 0..TAB inclusive
    int f = threadIdx.x;          // 0..127
    float dist = (float)t * (10.0f / (float)TAB);
    __shared__ float gs[F];
    __shared__ float t1[F];
    const float delta = 10.0f / 127.0f;
    const float coeff = -0.5f / (delta * delta);
    float off = (float)f * delta;
    float d = dist - off;
    gs[f] = expf(coeff * d * d);
    __syncthreads();
    float acc = nn1_b[f];
    for (int j = 0; j < F; ++j) acc += gs[j] * nn1_w[j * F + f];
    t1[f] = ssp(acc);
    __syncthreads();
    float acc2 = nn2_b[f];
    for (int j = 0; j < F; ++j) acc2 += t1[j] * nn2_w[j * F + f];
    wtab[(size_t)t * F + f] = acc2;
}

// ---------------- batch-aware kNN: wave per query, 64-bin d2 select ----------------
// Only points with d2 < 100 matter downstream (cosine cutoff == 0 at dist >= 10);
// under-full queries are padded with an arbitrary far point (contributes exactly 0).
__global__ __launch_bounds__(256) void knn_kernel(const float* __restrict__ posq,
                                                  const float4* __restrict__ posc4,
                                                  const int* __restrict__ bq,
                                                  const int* __restrict__ ctx_start,
                                                  int* __restrict__ nbr, int Nq) {
    __shared__ unsigned char sbin[4][BINCAP];
    __shared__ int hist[4][KBINS];
    __shared__ unsigned bkey[4][BCAP];
    __shared__ int bidx[4][BCAP];
    __shared__ int s_nwin[4], s_nbnd[4];

    int tid = threadIdx.x;
    int lane = tid & 63;
    int w = tid >> 6;
    int q = blockIdx.x * 4 + w;
    bool active = q < Nq;
    int qc = active ? q : 0;

    hist[w][lane] = 0;
    if (lane == 0) { s_nwin[w] = 0; s_nbnd[w] = 0; }

    float qx = posq[qc * 3 + 0];
    float qy = posq[qc * 3 + 1];
    float qz = posq[qc * 3 + 2];
    int b = bq[qc];
    int c0 = ctx_start[b];
    int c1 = ctx_start[b + 1];
    int seg = active ? (c1 - c0) : 0;
    __syncthreads();

    const float SCALE = (float)KBINS / RCUT2;
    int farc = -1;

    // Pass A: bin every candidate; cache bin byte; histogram in-cutoff bins
    for (int i = lane; i < seg; i += 64) {
        float d2 = d2f4(posc4[c0 + i], qx, qy, qz);
        int bin = 255;
        if (d2 < RCUT2) {
            bin = (int)(d2 * SCALE);
            atomicAdd(&hist[w][bin], 1);
        }
        if (i < BINCAP) sbin[w][i] = (unsigned char)bin;
    }
    __syncthreads();

    // wave scan of own 64-bin histogram
    int h = hist[w][lane];
    int inc = h;
#pragma unroll
    for (int off = 1; off < 64; off <<= 1) {
        int v = __shfl_up(inc, off);
        if (lane >= off) inc += v;
    }
    unsigned long long bal = __ballot(inc >= K);
    int T, below;
    if (bal) {
        T = __ffsll(bal) - 1;
        below = __shfl(inc, T) - __shfl(h, T);
    } else {
        T = KBINS;           // fewer than K in cutoff: all in-cutoff bins win
        below = __shfl(inc, 63);
    }

    // Pass B: emit winners, collect boundary bin, remember one far point
    for (int i = lane; i < seg; i += 64) {
        int c = c0 + i;
        int bin;
        if (i < BINCAP) bin = sbin[w][i];
        else {
            float d2 = d2f4(posc4[c], qx, qy, qz);
            bin = (d2 < RCUT2) ? (int)(d2 * SCALE) : 255;
        }
        if (bin < T) {
            int p = atomicAdd(&s_nwin[w], 1);
            nbr[(size_t)q * K + p] = c;
        } else if (bin == T) {
            int p = atomicAdd(&s_nbnd[w], 1);
            if (p < BCAP) {
                float d2 = d2f4(posc4[c], qx, qy, qz);
                bkey[w][p] = __float_as_uint(d2);
                bidx[w][p] = c;
            }
        } else if (bin == 255) {
            farc = c;
        }
    }
#pragma unroll
    for (int off = 1; off < 64; off <<= 1) farc = max(farc, __shfl_xor(farc, off));
    if (farc < 0) farc = c0;
    __syncthreads();

    if (!active) return;
    int nb = min(s_nbnd[w], BCAP);
    int m = K - s_nwin[w];
    // wave-serial: pick m smallest from boundary list (expected ~4-8)
    for (int it = 0; it < m; ++it) {
        unsigned bestk = 0xFFFFFFFFu;
        int bestp = -1;
        for (int p = lane; p < nb; p += 64) {
            unsigned kk = bkey[w][p];
            if (kk < bestk) { bestk = kk; bestp = p; }
        }
#pragma unroll
        for (int off = 1; off < 64; off <<= 1) {
            unsigned ok = __shfl_xor(bestk, off);
            int op = __shfl_xor(bestp, off);
            if (ok < bestk) { bestk = ok; bestp = op; }
        }
        if (lane == 0) {
            if (bestk != 0xFFFFFFFFu && bestp >= 0) {
                nbr[(size_t)q * K + below + it] = bidx[w][bestp];
                bkey[w][bestp] = 0xFFFFFFFFu;
            } else {
                nbr[(size_t)q * K + below + it] = farc;   // pad: contributes 0
            }
        }
        __asm__ volatile("" ::: "memory");
    }
}

// ---------------- per-query edge aggregation: acc_f = sum_k C_k * W_k[f] * a_k[f] ----------------
__global__ __launch_bounds__(128) void agg_kernel(const float* __restrict__ posq,
                                                  const float4* __restrict__ posc4,
                                                  const int* __restrict__ nbr,
                                                  const float* __restrict__ ctx_feat,
                                                  const float* __restrict__ wtab,
                                                  float* __restrict__ yacc,
                                                  float* __restrict__ ysc, int Nq) {
    int q = blockIdx.x;
    int f = threadIdx.x;
    __shared__ int sj[K];
    __shared__ int si0[K];
    __shared__ float sC[K];
    __shared__ float sfr[K];

    if (f < K) {
        int j = nbr[(size_t)q * K + f];
        sj[f] = j;
        float4 p = posc4[j];
        float dx = posq[q * 3 + 0] - p.x;
        float dy = posq[q * 3 + 1] - p.y;
        float dz = posq[q * 3 + 2] - p.z;
        float dist = sqrtf(dx * dx + dy * dy + dz * dz);
        float C = 0.0f, fr = 0.0f;
        int i0 = 0;
        if (dist <= 10.0f) {
            C = 0.5f * (cosf(dist * 0.31415926535897931f) + 1.0f);
            float u = dist * ((float)TAB / 10.0f);
            i0 = (int)u;
            if (i0 > TAB - 1) i0 = TAB - 1;
            fr = u - (float)i0;
        }
        sC[f] = C; si0[f] = i0; sfr[f] = fr;
    }
    __syncthreads();

    float acc = 0.0f;
    float csum = 0.0f;
    for (int k = 0; k < K; ++k) {
        float C = sC[k];
        csum += C;
        if (C == 0.0f) continue;
        int i0 = si0[k];
        float fr = sfr[k];
        int j = sj[k];
        float w0 = wtab[(size_t)i0 * F + f];
        float w1 = wtab[(size_t)(i0 + 1) * F + f];
        float W = w0 + fr * (w1 - w0);
        float a = ctx_feat[(size_t)j * F + f];
        acc += C * (W * a);
    }
    yacc[(size_t)q * F + f] = acc;
    if (f == 0) ysc[q] = csum;
}

// ---------------- heads: y = acc@lin2 + sC*lin2_b; cls/prop MLPs ----------------
__global__ __launch_bounds__(128) void head_kernel(const float* __restrict__ yacc,
                                                   const float* __restrict__ ysc,
                                                   const float* __restrict__ lin2_w,
                                                   const float* __restrict__ lin2_b,
                                                   const float* __restrict__ cls1_w,
                                                   const float* __restrict__ cls1_b,
                                                   const float* __restrict__ cls2_w,
                                                   const float* __restrict__ cls2_b,
                                                   const float* __restrict__ prop1_w,
                                                   const float* __restrict__ prop1_b,
                                                   const float* __restrict__ prop2_w,
                                                   const float* __restrict__ prop2_b,
                                                   float* __restrict__ out_cls,
                                                   float* __restrict__ out_ind, int Nq) {
    int q0 = blockIdx.x * QB;
    int f = threadIdx.x;
    __shared__ float sa[QB][F];
    __shared__ float ssc[QB];
    __shared__ float sy[QB][F];
    __shared__ float sc1[QB][F];
    __shared__ float sp1[QB][F];

#pragma unroll
    for (int qq = 0; qq < QB; ++qq) {
        int q = q0 + qq;
        sa[qq][f] = (q < Nq) ? yacc[(size_t)q * F + f] : 0.0f;
    }
    if (f < QB) ssc[f] = (q0 + f < Nq) ? ysc[q0 + f] : 0.0f;
    __syncthreads();

    // y = acc @ lin2_w + sC * lin2_b
    float y[QB];
    float lb = lin2_b[f];
#pragma unroll
    for (int qq = 0; qq < QB; ++qq) y[qq] = ssc[qq] * lb;
    for (int j = 0; j < F; ++j) {
        float w = lin2_w[j * F + f];
#pragma unroll
        for (int qq = 0; qq < QB; ++qq) y[qq] += sa[qq][j] * w;
    }
#pragma unroll
    for (int qq = 0; qq < QB; ++qq) sy[qq][f] = y[qq];
    __syncthreads();

    // c1 = ssp(y@cls1+b), p1 = ssp(y@prop1+b)
    float c1[QB], p1[QB];
    float cb = cls1_b[f], pb = prop1_b[f];
#pragma unroll
    for (int qq = 0; qq < QB; ++qq) { c1[qq] = cb; p1[qq] = pb; }
    for (int j = 0; j < F; ++j) {
        float wc = cls1_w[j * F + f];
        float wp = prop1_w[j * F + f];
#pragma unroll
        for (int qq = 0; qq < QB; ++qq) {
            float yv = sy[qq][j];
            c1[qq] += yv * wc;
            p1[qq] += yv * wp;
        }
    }
#pragma unroll
    for (int qq = 0; qq < QB; ++qq) {
        sc1[qq][f] = ssp(c1[qq]);
        sp1[qq][f] = ssp(p1[qq]);
    }
    __syncthreads();

    // tails: 7 cls outputs + 8 ind outputs per query
    int qq = f >> 4;
    int c = f & 15;
    int q = q0 + qq;
    if (q < Nq) {
        if (c < 7) {
            float acc = cls2_b[c];
            for (int j = 0; j < F; ++j) acc += sc1[qq][j] * cls2_w[j * 7 + c];
            out_cls[(size_t)q * 7 + c] = acc;
        } else if (c < 15) {
            int cc = c - 7;
            float acc = prop2_b[cc];
            for (int j = 0; j < F; ++j) acc += sp1[qq][j] * prop2_w[j * 8 + cc];
            out_ind[(size_t)q * 8 + cc] = acc;
        }
    }
}

extern "C" void kernel_launch(void* const* d_in, const int* in_sizes, int n_in,
                              void* d_out, int out_size, void* d_ws, size_t ws_size,
                              hipStream_t stream) {
    const float* posq   = (const float*)d_in[0];
    const float* posc   = (const float*)d_in[1];
    const float* attr   = (const float*)d_in[2];
    const int*   bq     = (const int*)d_in[3];
    const int*   bc     = (const int*)d_in[4];
    const float* lin1_w = (const float*)d_in[5];
    const float* lin2_w = (const float*)d_in[6];
    const float* lin2_b = (const float*)d_in[7];
    const float* nn1_w  = (const float*)d_in[8];
    const float* nn1_b  = (const float*)d_in[9];
    const float* nn2_w  = (const float*)d_in[10];
    const float* nn2_b  = (const float*)d_in[11];
    const float* cls1_w = (const float*)d_in[12];
    const float* cls1_b = (const float*)d_in[13];
    const float* cls2_w = (const float*)d_in[14];
    const float* cls2_b = (const float*)d_in[15];
    const float* prop1_w = (const float*)d_in[16];
    const float* prop1_b = (const float*)d_in[17];
    const float* prop2_w = (const float*)d_in[18];
    const float* prop2_b = (const float*)d_in[19];

    int Nq = in_sizes[0] / 3;
    int Nc = in_sizes[1] / 3;

    char* ws = (char*)d_ws;
    size_t off = 0;
    auto alloc = [&](size_t bytes) {
        off = (off + 255) & ~(size_t)255;
        void* p = ws + off;
        off += bytes;
        return p;
    };
    int*    ctx_start = (int*)alloc((BMAX + 1) * sizeof(int));
    int*    nbr       = (int*)alloc((size_t)Nq * K * sizeof(int));
    float*  ctx_feat  = (float*)alloc((size_t)Nc * F * sizeof(float));
    float*  wtab      = (float*)alloc((size_t)(TAB + 1) * F * sizeof(float));
    float*  yacc      = (float*)alloc((size_t)Nq * F * sizeof(float));
    float*  ysc       = (float*)alloc((size_t)Nq * sizeof(float));
    float4* posc4     = (float4*)alloc((size_t)Nc * sizeof(float4));
    (void)ws_size;

    float* out_cls = (float*)d_out;
    float* out_ind = out_cls + (size_t)Nq * 7;

    seg_kernel<<<dim3(1), dim3(32), 0, stream>>>(bc, Nc, ctx_start);
    pad_kernel<<<dim3((Nc + 255) / 256), dim3(256), 0, stream>>>(posc, posc4, Nc);
    feat_kernel<<<dim3((Nc + 7) / 8), dim3(128), 0, stream>>>(attr, lin1_w, ctx_feat, Nc);
    wtab_kernel<<<dim3(TAB + 1), dim3(128), 0, stream>>>(nn1_w, nn1_b, nn2_w, nn2_b, wtab);
    knn_kernel<<<dim3((Nq + 3) / 4), dim3(256), 0, stream>>>(posq, posc4, bq, ctx_start, nbr, Nq);
    agg_kernel<<<dim3(Nq), dim3(128), 0, stream>>>(posq, posc4, nbr, ctx_feat, wtab, yacc, ysc, Nq);
    head_kernel<<<dim3((Nq + QB - 1) / QB), dim3(128), 0, stream>>>(
        yacc, ysc, lin2_w, lin2_b, cls1_w, cls1_b, cls2_w, cls2_b,
        prop1_w, prop1_b, prop2_w, prop2_b, out_cls, out_ind, Nq);
}

// Round 4
// 159.089 us; speedup vs baseline: 2.5875x; 1.0535x over previous
//
#include <hip/hip_runtime.h>
#include <math.h>

#define K 32
#define F 128
#define H 256
#define TAB 4096
#define QB 8
#define BMAX 16
#define RCUT2 100.0f
#define KBINS 64
#define BINCAP 2560
#define BCAP 128
#define FP 132   // padded LDS row stride (16B-aligned, bank-skewed)

__device__ __forceinline__ float ssp(float x) {
    // jax.nn.softplus(x) - log(2)
    return fmaxf(x, 0.0f) + log1pf(expf(-fabsf(x))) - 0.69314718055994531f;
}

// d2 with pinned fma contraction so pass A and pass B agree bit-exactly
__device__ __forceinline__ float d2f4(float4 p, float qx, float qy, float qz) {
    float dx = qx - p.x;
    float dy = qy - p.y;
    float dz = qz - p.z;
    return fmaf(dz, dz, fmaf(dy, dy, dx * dx));
}

// ---------------- segment boundaries of sorted batch_ctx ----------------
__global__ void seg_kernel(const int* __restrict__ bc, int Nc, int* __restrict__ ctx_start) {
    int b = threadIdx.x;
    if (b > BMAX) return;
    int lo = 0, hi = Nc;
    while (lo < hi) {
        int mid = (lo + hi) >> 1;
        if (bc[mid] < b) lo = mid + 1; else hi = mid;
    }
    ctx_start[b] = lo;
}

// ---------------- pad positions to float4 for vector loads ----------------
__global__ __launch_bounds__(256) void pad_kernel(const float* __restrict__ pos,
                                                  float4* __restrict__ pos4, int N) {
    int i = blockIdx.x * 256 + threadIdx.x;
    if (i < N) {
        pos4[i] = make_float4(pos[i * 3 + 0], pos[i * 3 + 1], pos[i * 3 + 2], 0.0f);
    }
}

// ---------------- ctx_feat = node_attr_ctx @ lin1_w  [Nc,H]x[H,F] ----------------
__global__ __launch_bounds__(128) void feat_kernel(const float* __restrict__ attr,
                                                   const float* __restrict__ lin1_w,
                                                   float* __restrict__ ctx_feat, int Nc) {
    const int R = 8;
    __shared__ float sa[R][H];
    int r0 = blockIdx.x * R;
    int tid = threadIdx.x;
    for (int i = tid; i < R * H; i += 128) {
        int r = i >> 8, h = i & (H - 1);
        int row = r0 + r;
        sa[r][h] = (row < Nc) ? attr[(size_t)row * H + h] : 0.0f;
    }
    __syncthreads();
    float acc[R];
#pragma unroll
    for (int r = 0; r < R; ++r) acc[r] = 0.0f;
    for (int h = 0; h < H; ++h) {
        float w = lin1_w[h * F + tid];
#pragma unroll
        for (int r = 0; r < R; ++r) acc[r] += sa[r][h] * w;
    }
#pragma unroll
    for (int r = 0; r < R; ++r) {
        int row = r0 + r;
        if (row < Nc) ctx_feat[(size_t)row * F + tid] = acc[r];
    }
}

// ---------------- W(dist) table: ssp(gs@nn1+b1)@nn2+b2 over dist grid ----------------
__global__ __launch_bounds__(128) void wtab_kernel(const float* __restrict__ nn1_w,
                                                   const float* __restrict__ nn1_b,
                                                   const float* __restrict__ nn2_w,
                                                   const float* __restrict__ nn2_b,
                                                   float* __restrict__ wtab) {
    int t = blockIdx.x;           // 0..TAB inclusive
    int f = threadIdx.x;          // 0..127
    float dist = (float)t * (10.0f / (float)TAB);
    __shared__ float gs[F];
    __shared__ float t1[F];
    const float delta = 10.0f / 127.0f;
    const float coeff = -0.5f / (delta * delta);
    float off = (float)f * delta;
    float d = dist - off;
    gs[f] = expf(coeff * d * d);
    __syncthreads();
    float acc = nn1_b[f];
    for (int j = 0; j < F; ++j) acc += gs[j] * nn1_w[j * F + f];
    t1[f] = ssp(acc);
    __syncthreads();
    float acc2 = nn2_b[f];
    for (int j = 0; j < F; ++j) acc2 += t1[j] * nn2_w[j * F + f];
    wtab[(size_t)t * F + f] = acc2;
}

// ---------------- batch-aware kNN: wave per query, 64-bin d2 select ----------------
__global__ __launch_bounds__(256) void knn_kernel(const float* __restrict__ posq,
                                                  const float4* __restrict__ posc4,
                                                  const int* __restrict__ bq,
                                                  const int* __restrict__ ctx_start,
                                                  int* __restrict__ nbr, int Nq) {
    __shared__ unsigned char sbin[4][BINCAP];
    __shared__ int hist[4][KBINS];
    __shared__ unsigned bkey[4][BCAP];
    __shared__ int bidx[4][BCAP];
    __shared__ int s_nwin[4], s_nbnd[4];

    int tid = threadIdx.x;
    int lane = tid & 63;
    int w = tid >> 6;
    int q = blockIdx.x * 4 + w;
    bool active = q < Nq;
    int qc = active ? q : 0;

    hist[w][lane] = 0;
    if (lane == 0) { s_nwin[w] = 0; s_nbnd[w] = 0; }

    float qx = posq[qc * 3 + 0];
    float qy = posq[qc * 3 + 1];
    float qz = posq[qc * 3 + 2];
    int b = bq[qc];
    int c0 = ctx_start[b];
    int c1 = ctx_start[b + 1];
    int seg = active ? (c1 - c0) : 0;
    __syncthreads();

    const float SCALE = (float)KBINS / RCUT2;
    int farc = -1;

    // Pass A: bin every candidate; cache bin byte; histogram in-cutoff bins
    for (int i = lane; i < seg; i += 64) {
        float d2 = d2f4(posc4[c0 + i], qx, qy, qz);
        int bin = 255;
        if (d2 < RCUT2) {
            bin = (int)(d2 * SCALE);
            atomicAdd(&hist[w][bin], 1);
        }
        if (i < BINCAP) sbin[w][i] = (unsigned char)bin;
    }
    __syncthreads();

    // wave scan of own 64-bin histogram
    int h = hist[w][lane];
    int inc = h;
#pragma unroll
    for (int off = 1; off < 64; off <<= 1) {
        int v = __shfl_up(inc, off);
        if (lane >= off) inc += v;
    }
    unsigned long long bal = __ballot(inc >= K);
    int T, below;
    if (bal) {
        T = __ffsll(bal) - 1;
        below = __shfl(inc, T) - __shfl(h, T);
    } else {
        T = KBINS;           // fewer than K in cutoff: all in-cutoff bins win
        below = __shfl(inc, 63);
    }

    // Pass B: emit winners, collect boundary bin, remember one far point
    for (int i = lane; i < seg; i += 64) {
        int c = c0 + i;
        int bin;
        if (i < BINCAP) bin = sbin[w][i];
        else {
            float d2 = d2f4(posc4[c], qx, qy, qz);
            bin = (d2 < RCUT2) ? (int)(d2 * SCALE) : 255;
        }
        if (bin < T) {
            int p = atomicAdd(&s_nwin[w], 1);
            nbr[(size_t)q * K + p] = c;
        } else if (bin == T) {
            int p = atomicAdd(&s_nbnd[w], 1);
            if (p < BCAP) {
                float d2 = d2f4(posc4[c], qx, qy, qz);
                bkey[w][p] = __float_as_uint(d2);
                bidx[w][p] = c;
            }
        } else if (bin == 255) {
            farc = c;
        }
    }
#pragma unroll
    for (int off = 1; off < 64; off <<= 1) farc = max(farc, __shfl_xor(farc, off));
    if (farc < 0) farc = c0;
    __syncthreads();

    if (!active) return;
    int nb = min(s_nbnd[w], BCAP);
    int m = K - s_nwin[w];
    // wave-serial: pick m smallest from boundary list (expected ~4-8)
    for (int it = 0; it < m; ++it) {
        unsigned bestk = 0xFFFFFFFFu;
        int bestp = -1;
        for (int p = lane; p < nb; p += 64) {
            unsigned kk = bkey[w][p];
            if (kk < bestk) { bestk = kk; bestp = p; }
        }
#pragma unroll
        for (int off = 1; off < 64; off <<= 1) {
            unsigned ok = __shfl_xor(bestk, off);
            int op = __shfl_xor(bestp, off);
            if (ok < bestk) { bestk = ok; bestp = op; }
        }
        if (lane == 0) {
            if (bestk != 0xFFFFFFFFu && bestp >= 0) {
                nbr[(size_t)q * K + below + it] = bidx[w][bestp];
                bkey[w][bestp] = 0xFFFFFFFFu;
            } else {
                nbr[(size_t)q * K + below + it] = farc;   // pad: contributes 0
            }
        }
        __asm__ volatile("" ::: "memory");
    }
}

// ---------------- per-query edge aggregation: acc_f = sum_k C_k * W_k[f] * a_k[f] ----------------
__global__ __launch_bounds__(128) void agg_kernel(const float* __restrict__ posq,
                                                  const float4* __restrict__ posc4,
                                                  const int* __restrict__ nbr,
                                                  const float* __restrict__ ctx_feat,
                                                  const float* __restrict__ wtab,
                                                  float* __restrict__ yacc,
                                                  float* __restrict__ ysc, int Nq) {
    int q = blockIdx.x;
    int f = threadIdx.x;
    __shared__ int sj[K];
    __shared__ int si0[K];
    __shared__ float sC[K];
    __shared__ float sfr[K];

    if (f < K) {
        int j = nbr[(size_t)q * K + f];
        sj[f] = j;
        float4 p = posc4[j];
        float dx = posq[q * 3 + 0] - p.x;
        float dy = posq[q * 3 + 1] - p.y;
        float dz = posq[q * 3 + 2] - p.z;
        float dist = sqrtf(dx * dx + dy * dy + dz * dz);
        float C = 0.0f, fr = 0.0f;
        int i0 = 0;
        if (dist <= 10.0f) {
            C = 0.5f * (cosf(dist * 0.31415926535897931f) + 1.0f);
            float u = dist * ((float)TAB / 10.0f);
            i0 = (int)u;
            if (i0 > TAB - 1) i0 = TAB - 1;
            fr = u - (float)i0;
        }
        sC[f] = C; si0[f] = i0; sfr[f] = fr;
    }
    __syncthreads();

    float acc = 0.0f;
    float csum = 0.0f;
    for (int k = 0; k < K; ++k) {
        float C = sC[k];
        csum += C;
        if (C == 0.0f) continue;
        int i0 = si0[k];
        float fr = sfr[k];
        int j = sj[k];
        float w0 = wtab[(size_t)i0 * F + f];
        float w1 = wtab[(size_t)(i0 + 1) * F + f];
        float W = w0 + fr * (w1 - w0);
        float a = ctx_feat[(size_t)j * F + f];
        acc += C * (W * a);
    }
    yacc[(size_t)q * F + f] = acc;
    if (f == 0) ysc[q] = csum;
}

// ---------------- heads: y = acc@lin2 + sC*lin2_b; cls/prop MLPs ----------------
// 256 threads: f = tid&127 (output feature), g = tid>>7 (query half, 4 queries each)
__global__ __launch_bounds__(256) void head_kernel(const float* __restrict__ yacc,
                                                   const float* __restrict__ ysc,
                                                   const float* __restrict__ lin2_w,
                                                   const float* __restrict__ lin2_b,
                                                   const float* __restrict__ cls1_w,
                                                   const float* __restrict__ cls1_b,
                                                   const float* __restrict__ cls2_w,
                                                   const float* __restrict__ cls2_b,
                                                   const float* __restrict__ prop1_w,
                                                   const float* __restrict__ prop1_b,
                                                   const float* __restrict__ prop2_w,
                                                   const float* __restrict__ prop2_b,
                                                   float* __restrict__ out_cls,
                                                   float* __restrict__ out_ind, int Nq) {
    const int QH = QB / 2;   // 4 queries per thread-group
    int q0 = blockIdx.x * QB;
    int tid = threadIdx.x;
    int f = tid & (F - 1);
    int g = tid >> 7;

    __shared__ float sa[QB][F];       // yacc rows (broadcast-read only)
    __shared__ float ssc[QB];
    __shared__ float sy[QB][FP];      // padded: 16B-aligned rows, bank-skewed
    __shared__ float sc1[QB][FP];
    __shared__ float sp1[QB][FP];

    // stage yacc rows: one coalesced float4 load (QB*F/4 == 256)
    if (q0 + QB <= Nq) {
        ((float4*)sa)[tid] = ((const float4*)(yacc + (size_t)q0 * F))[tid];
    } else {
        for (int i = tid; i < QB * F; i += 256) {
            int qq = i >> 7;
            sa[qq][i & (F - 1)] = (q0 + qq < Nq) ? yacc[(size_t)(q0 + qq) * F + (i & (F - 1))] : 0.0f;
        }
    }
    if (tid < QB) ssc[tid] = (q0 + tid < Nq) ? ysc[q0 + tid] : 0.0f;
    __syncthreads();

    // ---- stage A: y = sa @ lin2_w + ssc*lin2_b (each thread: 4 queries) ----
    {
        float y[QH];
        float lb = lin2_b[f];
#pragma unroll
        for (int i = 0; i < QH; ++i) y[i] = ssc[g * QH + i] * lb;
        for (int j = 0; j < F; j += 4) {
            float w0 = lin2_w[(j + 0) * F + f];
            float w1 = lin2_w[(j + 1) * F + f];
            float w2 = lin2_w[(j + 2) * F + f];
            float w3 = lin2_w[(j + 3) * F + f];
#pragma unroll
            for (int i = 0; i < QH; ++i) {
                float4 a4 = *(const float4*)&sa[g * QH + i][j];
                y[i] = fmaf(a4.x, w0, y[i]);
                y[i] = fmaf(a4.y, w1, y[i]);
                y[i] = fmaf(a4.z, w2, y[i]);
                y[i] = fmaf(a4.w, w3, y[i]);
            }
        }
#pragma unroll
        for (int i = 0; i < QH; ++i) sy[g * QH + i][f] = y[i];
    }
    __syncthreads();

    // ---- stage B: c1 = ssp(y@cls1+b), p1 = ssp(y@prop1+b) ----
    {
        float c1[QH], p1[QH];
        float cb = cls1_b[f], pb = prop1_b[f];
#pragma unroll
        for (int i = 0; i < QH; ++i) { c1[i] = cb; p1[i] = pb; }
        for (int j = 0; j < F; j += 4) {
            float wc0 = cls1_w[(j + 0) * F + f];
            float wc1 = cls1_w[(j + 1) * F + f];
            float wc2 = cls1_w[(j + 2) * F + f];
            float wc3 = cls1_w[(j + 3) * F + f];
            float wp0 = prop1_w[(j + 0) * F + f];
            float wp1 = prop1_w[(j + 1) * F + f];
            float wp2 = prop1_w[(j + 2) * F + f];
            float wp3 = prop1_w[(j + 3) * F + f];
#pragma unroll
            for (int i = 0; i < QH; ++i) {
                float4 y4 = *(const float4*)&sy[g * QH + i][j];
                c1[i] = fmaf(y4.x, wc0, c1[i]);
                c1[i] = fmaf(y4.y, wc1, c1[i]);
                c1[i] = fmaf(y4.z, wc2, c1[i]);
                c1[i] = fmaf(y4.w, wc3, c1[i]);
                p1[i] = fmaf(y4.x, wp0, p1[i]);
                p1[i] = fmaf(y4.y, wp1, p1[i]);
                p1[i] = fmaf(y4.z, wp2, p1[i]);
                p1[i] = fmaf(y4.w, wp3, p1[i]);
            }
        }
#pragma unroll
        for (int i = 0; i < QH; ++i) {
            sc1[g * QH + i][f] = ssp(c1[i]);
            sp1[g * QH + i][f] = ssp(p1[i]);
        }
    }
    __syncthreads();

    // ---- tails: 8 queries x 15 outputs; 32 threads per query, c<15 active ----
    {
        int qq = tid >> 5;            // 0..7
        int c = tid & 31;             // 0..31
        int q = q0 + qq;
        if (q < Nq && c < 15) {
            if (c < 7) {
                float acc = cls2_b[c];
                for (int j = 0; j < F; ++j) acc = fmaf(sc1[qq][j], cls2_w[j * 7 + c], acc);
                out_cls[(size_t)q * 7 + c] = acc;
            } else {
                int cc = c - 7;
                float acc = prop2_b[cc];
                for (int j = 0; j < F; ++j) acc = fmaf(sp1[qq][j], prop2_w[j * 8 + cc], acc);
                out_ind[(size_t)q * 8 + cc] = acc;
            }
        }
    }
}

extern "C" void kernel_launch(void* const* d_in, const int* in_sizes, int n_in,
                              void* d_out, int out_size, void* d_ws, size_t ws_size,
                              hipStream_t stream) {
    const float* posq   = (const float*)d_in[0];
    const float* posc   = (const float*)d_in[1];
    const float* attr   = (const float*)d_in[2];
    const int*   bq     = (const int*)d_in[3];
    const int*   bc     = (const int*)d_in[4];
    const float* lin1_w = (const float*)d_in[5];
    const float* lin2_w = (const float*)d_in[6];
    const float* lin2_b = (const float*)d_in[7];
    const float* nn1_w  = (const float*)d_in[8];
    const float* nn1_b  = (const float*)d_in[9];
    const float* nn2_w  = (const float*)d_in[10];
    const float* nn2_b  = (const float*)d_in[11];
    const float* cls1_w = (const float*)d_in[12];
    const float* cls1_b = (const float*)d_in[13];
    const float* cls2_w = (const float*)d_in[14];
    const float* cls2_b = (const float*)d_in[15];
    const float* prop1_w = (const float*)d_in[16];
    const float* prop1_b = (const float*)d_in[17];
    const float* prop2_w = (const float*)d_in[18];
    const float* prop2_b = (const float*)d_in[19];

    int Nq = in_sizes[0] / 3;
    int Nc = in_sizes[1] / 3;

    char* ws = (char*)d_ws;
    size_t off = 0;
    auto alloc = [&](size_t bytes) {
        off = (off + 255) & ~(size_t)255;
        void* p = ws + off;
        off += bytes;
        return p;
    };
    int*    ctx_start = (int*)alloc((BMAX + 1) * sizeof(int));
    int*    nbr       = (int*)alloc((size_t)Nq * K * sizeof(int));
    float*  ctx_feat  = (float*)alloc((size_t)Nc * F * sizeof(float));
    float*  wtab      = (float*)alloc((size_t)(TAB + 1) * F * sizeof(float));
    float*  yacc      = (float*)alloc((size_t)Nq * F * sizeof(float));
    float*  ysc       = (float*)alloc((size_t)Nq * sizeof(float));
    float4* posc4     = (float4*)alloc((size_t)Nc * sizeof(float4));
    (void)ws_size;

    float* out_cls = (float*)d_out;
    float* out_ind = out_cls + (size_t)Nq * 7;

    seg_kernel<<<dim3(1), dim3(32), 0, stream>>>(bc, Nc, ctx_start);
    pad_kernel<<<dim3((Nc + 255) / 256), dim3(256), 0, stream>>>(posc, posc4, Nc);
    feat_kernel<<<dim3((Nc + 7) / 8), dim3(128), 0, stream>>>(attr, lin1_w, ctx_feat, Nc);
    wtab_kernel<<<dim3(TAB + 1), dim3(128), 0, stream>>>(nn1_w, nn1_b, nn2_w, nn2_b, wtab);
    knn_kernel<<<dim3((Nq + 3) / 4), dim3(256), 0, stream>>>(posq, posc4, bq, ctx_start, nbr, Nq);
    agg_kernel<<<dim3(Nq), dim3(128), 0, stream>>>(posq, posc4, nbr, ctx_feat, wtab, yacc, ysc, Nq);
    head_kernel<<<dim3((Nq + QB - 1) / QB), dim3(256), 0, stream>>>(
        yacc, ysc, lin2_w, lin2_b, cls1_w, cls1_b, cls2_w, cls2_b,
        prop1_w, prop1_b, prop2_w, prop2_b, out_cls, out_ind, Nq);
}